// Round 10
// baseline (2784.781 us; speedup 1.0000x reference)
//
#include <hip/hip_runtime.h>
#include <hip/hip_bf16.h>

// LSTM: SEQ=64, IN=100000, H=50 (4H=200 gates)
// x[64,100000] f32, Wi[100000,200] f32, bi[200], Wh[50,200], bh[200] -> h[50]
//
// R17: k1 REWRITTEN AS PURE-VALU FP32. R16's counters (MfmaUtil 7%,
//      VALUBusy 12%, HBM 23%, occupancy 16% — everything idle, 47.8us
//      constant across 5 structural variants) showed the MFMA formulation's
//      staged dependency chain (split->pack->LDS->frag->MFMA) was the
//      limiter, not orchestration. At 24 FLOP/B this GEMM is perfectly
//      balanced for fp32 VALU: 2.56 GFLOP/157TF = 16.3us == HBM floor.
//      New k1: lane=s (64), wave owns 52 gates, acc[52]/lane; Wi staged
//      f32 to LDS (no hi/lo split, no transpose); x lane-private in regs;
//      inner: ds_read_b128 broadcast (conflict-free) -> 4 indep FMAs.
//      1664 FMA : 416 LDS reads per wave-tile -> VALU-bound ~17.8us chip.
//      Dual-regset 2-deep Wi prefetch, dbuf LDS, 1 lgkm-only barrier/tile.
//      fp32 is MORE accurate than the passing bf16 hi/lo emulation;
//      association changes proven tolerated (R16, absmax 0.0).
// K2: R16 (512 partials, slices of 16). K3: frozen R15.

#define K_DIM 100000
#define NG 200
#define NS 64
#define TK 32                    // 100000 = 32 * 3125 exactly
#define NBLK 512
#define NTILES 3125              // K_DIM / TK
#define CELLS (NS * NG)          // 12800
#define CELLS4 (CELLS / 4)       // 3200
#define GPW 52                   // gates per wave (4*52 = 208, cols 200..207 zero)
#define WROW 208                 // LDS row length in floats
#define NWTASK 1600              // Wi f4 stage tasks per tile: 32 rows x 50 f4

typedef unsigned int u32;

// raw workgroup barrier WITHOUT the compiler's vmcnt(0) drain:
// own LDS ops retired (lgkmcnt covers ds_read+ds_write), collective via
// s_barrier; sched_barrier(0) stops the compiler hoisting later LDS ops
// above it. Global prefetch loads stay outstanding.
#define TILE_BARRIER() do {                                   \
    asm volatile("s_waitcnt lgkmcnt(0)" ::: "memory");        \
    __builtin_amdgcn_s_barrier();                             \
    __builtin_amdgcn_sched_barrier(0);                        \
} while (0)

// broadcast lane j's value of v to all lanes (j compile-time; ignores exec)
static __device__ __forceinline__ float rl(float v, int j) {
    return __int_as_float(__builtin_amdgcn_readlane(__float_as_int(v), j));
}

__global__ __launch_bounds__(256, 2) void k1_gemm_partial(
    const float* __restrict__ x, const float* __restrict__ Wi,
    float* __restrict__ partial)
{
    // double-buffered Wi slab, f32 [k][g]: 2 x 32 x 208 x 4B = 53.2 KB
    __shared__ __align__(16) float WL[2][TK][WROW];

    const int t     = threadIdx.x;       // 0..255
    const int lane  = t & 63;            // = s row (exactly 64 rows)
    const int w     = t >> 6;            // wave 0..3
    const int wbase = w * GPW;           // first gate of this wave

    // zero pad cols 200..207 (both buffers; never overwritten by staging)
    for (int i = t; i < 2 * TK * 8; i += 256) {
        int b = i >> 8, r = (i >> 3) & 31, c = 200 + (i & 7);
        WL[b][r][c] = 0.f;
    }

    // Wi staging tasks: task = t + 256*j ; row=task/50, col4=task%50.
    // t<64: 7 tasks (last ids 1536..1599), else 6. Computed once.
    const int nt = (t < 64) ? 7 : 6;
    int trow[7], tcol[7];
#pragma unroll
    for (int j = 0; j < 7; ++j) {
        int task = t + 256 * j;
        trow[j] = task / 50;
        tcol[j] = (task - 50 * trow[j]) * 4;
    }

    auto load_w = [&](int ti, float4 (&wr)[7]) {
        const float* src = Wi + (size_t)ti * TK * NG;
#pragma unroll
        for (int j = 0; j < 7; ++j)
            if (j < nt) wr[j] = *(const float4*)(src + trow[j] * NG + tcol[j]);
    };
    auto stage_w = [&](const float4 (&wr)[7], int p) {
#pragma unroll
        for (int j = 0; j < 7; ++j)
            if (j < nt) *(float4*)&WL[p][trow[j]][tcol[j]] = wr[j];
    };
    auto load_x = [&](int ti, float4 (&xr)[8]) {
        const float* src = x + (size_t)lane * K_DIM + (size_t)ti * TK;
#pragma unroll
        for (int j = 0; j < 8; ++j) xr[j] = *(const float4*)(src + 4 * j);
    };

    float acc[GPW];
#pragma unroll
    for (int j = 0; j < GPW; ++j) acc[j] = 0.f;

    auto compute = [&](const float4 (&xr)[8], int p) {
#pragma unroll
        for (int k = 0; k < TK; ++k) {
            float4 xv = xr[k >> 2];                       // compile-time idx
            float xk = (k & 3) == 0 ? xv.x : (k & 3) == 1 ? xv.y
                     : (k & 3) == 2 ? xv.z : xv.w;
            const float4* wrow = (const float4*)&WL[p][k][wbase];
#pragma unroll
            for (int q = 0; q < GPW / 4; ++q) {           // 13 quads
                float4 w4 = wrow[q];                      // broadcast b128
                acc[4 * q + 0] = fmaf(xk, w4.x, acc[4 * q + 0]);
                acc[4 * q + 1] = fmaf(xk, w4.y, acc[4 * q + 1]);
                acc[4 * q + 2] = fmaf(xk, w4.z, acc[4 * q + 2]);
                acc[4 * q + 3] = fmaf(xk, w4.w, acc[4 * q + 3]);
            }
        }
    };

    // ---- prologue: wA<-t0, wB<-t0+N (both <1024<3125); xP<-t0, xQ<-t0+N;
    //      stage wA->buf0 (vmcnt waits wA only; wB/x stay in flight);
    //      reload wA <- t0+2N ----
    float4 wA[7], wB[7], xP[8], xQ[8];
    const int ti0 = blockIdx.x;
    load_w(ti0,        wA);  load_x(ti0,        xP);
    load_w(ti0 + NBLK, wB);  load_x(ti0 + NBLK, xQ);
    stage_w(wA, 0);
    {
        int tf = ti0 + 2 * NBLK;
        if (tf < NTILES) load_w(tf, wA);
    }
    TILE_BARRIER();

    // ---- main loop (x2 for regset parity): iteration ti computes buf[p]
    //      with lane-private x; stages the other W-set into buf[p^1];
    //      reloads W 2 tiles ahead and x after its last read. One
    //      lgkm-only barrier per tile; prefetches survive it. ----
    int p = 0;
    int ti = ti0;
    while (ti < NTILES) {
        {   // stage from wB, compute with xP
            int tn = ti + NBLK;
            if (tn < NTILES) {
                stage_w(wB, p ^ 1);
                int tf = tn + 2 * NBLK;
                if (tf < NTILES) load_w(tf, wB);
            }
            compute(xP, p);
            int xf = ti + 2 * NBLK;
            if (xf < NTILES) load_x(xf, xP);   // xP dead after compute
            TILE_BARRIER();
            p ^= 1; ti += NBLK;
        }
        if (ti >= NTILES) break;
        {   // stage from wA, compute with xQ
            int tn = ti + NBLK;
            if (tn < NTILES) {
                stage_w(wA, p ^ 1);
                int tf = tn + 2 * NBLK;
                if (tf < NTILES) load_w(tf, wA);
            }
            compute(xQ, p);
            int xf = ti + 2 * NBLK;
            if (xf < NTILES) load_x(xf, xQ);
            TILE_BARRIER();
            p ^= 1; ti += NBLK;
        }
    }

    // epilogue: partial[b][s][g]; lane=s, gates wbase..wbase+51 (w3: ..199).
    // 16B-aligned f4 stores (200%4==0, 52%4==0).
    float* base = partial + (size_t)blockIdx.x * CELLS + (size_t)lane * NG + wbase;
    const int nq = (w == 3) ? 11 : 13;        // w3 covers 156..199 = 11 quads
#pragma unroll
    for (int q = 0; q < 13; ++q)
        if (q < nq)
            *(float4*)(base + 4 * q) = make_float4(acc[4 * q], acc[4 * q + 1],
                                                  acc[4 * q + 2], acc[4 * q + 3]);
}

__global__ __launch_bounds__(512) void k2_reduce(
    const float* __restrict__ partial, const float* __restrict__ bi,
    const float* __restrict__ bh, float* __restrict__ gates)
{
    __shared__ float4 red[512];
    const int tid   = threadIdx.x;
    const int fid   = tid & 15;                 // f4-cell within block
    const int slice = tid >> 4;                 // 0..31, each sums 16 b's
    const int g4    = blockIdx.x * 16 + fid;    // 0..3199

    const float4* p4 = (const float4*)partial;
    float4 sum = make_float4(0.f, 0.f, 0.f, 0.f);
#pragma unroll 4
    for (int b = slice * 16; b < slice * 16 + 16; ++b) {
        float4 v = p4[(size_t)b * CELLS4 + g4];
        sum.x += v.x; sum.y += v.y; sum.z += v.z; sum.w += v.w;
    }
    red[tid] = sum;
    __syncthreads();
    if (tid < 16) {
        float4 tot = red[tid];
#pragma unroll
        for (int p = 1; p < 32; ++p) {
            float4 v = red[p * 16 + tid];
            tot.x += v.x; tot.y += v.y; tot.z += v.z; tot.w += v.w;
        }
        int gg = (g4 * 4) % NG;                 // NG%4==0: never wraps mid-f4
        float4 b1 = *(const float4*)(bi + gg);
        float4 b2 = *(const float4*)(bh + gg);
        tot.x += b1.x + b2.x; tot.y += b1.y + b2.y;
        tot.z += b1.z + b2.z; tot.w += b1.w + b2.w;
        ((float4*)gates)[g4] = tot;
    }
}

__global__ __launch_bounds__(256)
__attribute__((amdgpu_waves_per_eu(1)))
void k3_lstm(
    const float* __restrict__ gates, const float* __restrict__ Wh,
    float* __restrict__ out)
{
    // 4 waves; wave w = gate type (0=i,1=f,2=g,3=o); lane l<50 = cell l.
    // 50 weights/lane in registers (R15: proven fast, frozen).
    __shared__ float act[2][NG];    // double-buffered by step parity
    const int tid = threadIdx.x;
    const int w   = tid >> 6;       // gate type
    const int l   = tid & 63;
    const bool al = (l < 50);
    const int  lc = al ? l : 49;    // idle lanes compute harmlessly on cell 49
    const int  gidx = w * 50 + lc;  // gate index in [0,200)

    float wv[50];                   // Wh column for this gate: Wh[j][gidx]
#pragma unroll
    for (int j = 0; j < 50; ++j) wv[j] = Wh[j * NG + gidx];

    const float* gp = gates + gidx;
    float gz = gp[0];
    float c = 0.f, h = 0.f;

    for (int s = 0; s < 64; ++s) {
        // prefetch next step's pre-activation (L2-hot; TILE_BARRIER does not
        // drain vmcnt, so this stays in flight under the chain + barrier)
        float nz = (s < 63) ? gp[(s + 1) * NG] : 0.f;

        // z: verbatim R0 association — 4 chains by j mod 4, gz seeds a0,
        // tail j=48,49 -> a0,a1, z=(a0+a1)+(a2+a3). h broadcast intra-wave.
        float a0 = gz, a1 = 0.f, a2 = 0.f, a3 = 0.f;
#pragma unroll
        for (int j = 0; j < 48; j += 4) {
            a0 = fmaf(rl(h, j),     wv[j],     a0);
            a1 = fmaf(rl(h, j + 1), wv[j + 1], a1);
            a2 = fmaf(rl(h, j + 2), wv[j + 2], a2);
            a3 = fmaf(rl(h, j + 3), wv[j + 3], a3);
        }
        a0 = fmaf(rl(h, 48), wv[48], a0);
        a1 = fmaf(rl(h, 49), wv[49], a1);
        float z = (a0 + a1) + (a2 + a3);

        // activation: waves 0,1,3 sigmoid; wave 2 tanh (identical exprs to R0)
        float e = __expf(-z);
        float av;
        if (w == 2) { float e2 = e * e; av = (1.f - e2) / (1.f + e2); }
        else        { av = 1.f / (1.f + e); }
        if (al) act[s & 1][gidx] = av;

        TILE_BARRIER();   // act[s&1] published; lgkmcnt-only (prefetch lives).
        // Race-free: next write to act[s&1] is step s+2, behind barrier(s+1);
        // all step-s readers below finish before passing barrier(s+1).

        // redundant identical c/h update in EVERY wave (same inputs ->
        // same bits) -> no second barrier; h stays wave-local for readlane.
        float iv = act[s & 1][lc];
        float fv = act[s & 1][50 + lc];
        float gv = act[s & 1][100 + lc];
        float ov = act[s & 1][150 + lc];
        c = fmaf(fv, c, iv * gv);
        float e2c = __expf(-2.f * c);
        h = ov * (1.f - e2c) / (1.f + e2c);

        gz = nz;
    }
    if (w == 0 && al) out[l] = h;
}

extern "C" void kernel_launch(void* const* d_in, const int* in_sizes, int n_in,
                              void* d_out, int out_size, void* d_ws, size_t ws_size,
                              hipStream_t stream)
{
    const float* x  = (const float*)d_in[0];
    const float* Wi = (const float*)d_in[1];
    const float* bi = (const float*)d_in[2];
    const float* Wh = (const float*)d_in[3];
    const float* bh = (const float*)d_in[4];
    float* out = (float*)d_out;

    float* partial = (float*)d_ws;                    // 512*12800 f32 = 26.2 MB
    float* gates   = partial + (size_t)NBLK * CELLS;  // 12800 f32

    k1_gemm_partial<<<NBLK, 256, 0, stream>>>(x, Wi, partial);
    k2_reduce<<<CELLS4 / 16, 512, 0, stream>>>(partial, bi, bh, gates);
    k3_lstm<<<1, 256, 0, stream>>>(gates, Wh, out);
}